// Round 1
// baseline (555.878 us; speedup 1.0000x reference)
//
#include <hip/hip_runtime.h>

// Problem constants (reference: B=16, N=2048, D=64, fp32 in/out)
#define Bb 16
#define Nn 2048
#define Dd 64

typedef __attribute__((ext_vector_type(8))) short s16x8;  // 8 bf16 (A/B frag, 16x16x32)
typedef __attribute__((ext_vector_type(4))) short s16x4;  // 4 bf16 (A/B frag, 16x16x16)
typedef __attribute__((ext_vector_type(4))) float fx4;    // MFMA accumulator

__device__ __forceinline__ unsigned short f2bf(float f) {
  union { float f; unsigned u; } v; v.f = f;
  unsigned r = v.u + 0x7FFFu + ((v.u >> 16) & 1u);  // round-to-nearest-even
  return (unsigned short)(r >> 16);
}

// ---- prep 1: K fp32 -> bf16 (row-major [B][N][D]) -------------------------
__global__ void k_cvtK(const float* __restrict__ K, unsigned short* __restrict__ Kb) {
  int i = blockIdx.x * 256 + threadIdx.x;
  float4 f = ((const float4*)K)[i];
  ushort4 o;
  o.x = f2bf(f.x); o.y = f2bf(f.y); o.z = f2bf(f.z); o.w = f2bf(f.w);
  ((ushort4*)Kb)[i] = o;
}

// ---- prep 2: V [B][N][D] fp32 -> VT [B][D][N] bf16 ------------------------
__global__ void k_transV(const float* __restrict__ V, unsigned short* __restrict__ VT) {
  __shared__ float tile[32][33];
  int b = blockIdx.z;
  int j0 = blockIdx.x * 32, d0 = blockIdx.y * 32;
  int tx = threadIdx.x, ty = threadIdx.y;  // block (32,8)
  const float* Vb = V + (size_t)b * Nn * Dd;
  unsigned short* Tb = VT + (size_t)b * Dd * Nn;
  for (int r = ty; r < 32; r += 8)
    tile[r][tx] = Vb[(size_t)(j0 + r) * Dd + d0 + tx];
  __syncthreads();
  for (int r = ty; r < 32; r += 8)
    Tb[(size_t)(d0 + r) * Nn + j0 + tx] = f2bf(tile[tx][r]);
}

// ---- main fused attention -------------------------------------------------
// Block = 256 threads = 4 independent waves; wave handles 16 q rows.
// S' = K·Q^T via mfma_f32_16x16x32_bf16: C-layout col(lane&15)=q,
// row(quad*4+reg)=k  ->  softmax stats are lane-local; P' registers match the
// A-operand layout of mfma_f32_16x16x16bf16_1k (k = quad*4+j) so PV needs no
// transpose/LDS. No __shared__, no __syncthreads in this kernel.
__global__ __launch_bounds__(256) void k_attn(
    const float* __restrict__ Q, const unsigned short* __restrict__ Kbf,
    const unsigned short* __restrict__ VTbf, const float* __restrict__ scale_p,
    float* __restrict__ ctx, float* att) {
  const int b = blockIdx.y;
  const int q0 = blockIdx.x * 64;
  const int tid = threadIdx.x;
  const int wave = tid >> 6, lane = tid & 63;
  const int nl = lane & 15, quad = lane >> 4;
  const int qrow = q0 + wave * 16 + nl;
  const float c2 = scale_p[0] * 1.44269504088896341f;  // scale * log2(e)

  // Q fragment (B operand): B[n=q][k = kt*32 + quad*8 + j], fp32->bf16 inline
  s16x8 qb[2];
  {
    const float* qp = Q + ((size_t)b * Nn + qrow) * Dd + quad * 8;
#pragma unroll
    for (int kt = 0; kt < 2; ++kt) {
      float4 f0 = *(const float4*)(qp + kt * 32);
      float4 f1 = *(const float4*)(qp + kt * 32 + 4);
      s16x8 t;
      t[0] = (short)f2bf(f0.x); t[1] = (short)f2bf(f0.y);
      t[2] = (short)f2bf(f0.z); t[3] = (short)f2bf(f0.w);
      t[4] = (short)f2bf(f1.x); t[5] = (short)f2bf(f1.y);
      t[6] = (short)f2bf(f1.z); t[7] = (short)f2bf(f1.w);
      qb[kt] = t;
    }
  }
  const unsigned short* Kb = Kbf + (size_t)b * Nn * Dd;
  const unsigned short* VTb = VTbf + (size_t)b * Dd * Nn;
  float* attb = att + (size_t)b * Nn * Nn;

  float m = -3.0e38f, l = 0.0f;

  // ---- sweep 1: online max / sum (lane-local; each lane sees a fixed q) ----
  for (int t = 0; t < 16; ++t) {
    const int k0 = t * 128;
    fx4 s[8];
#pragma unroll
    for (int nt = 0; nt < 8; ++nt) s[nt] = (fx4){0.f, 0.f, 0.f, 0.f};
#pragma unroll
    for (int nt = 0; nt < 8; ++nt) {
      const s16x8* ka =
          (const s16x8*)(Kb + ((size_t)(k0 + nt * 16 + nl)) * Dd + quad * 8);
      s[nt] = __builtin_amdgcn_mfma_f32_16x16x32_bf16(ka[0], qb[0], s[nt], 0, 0, 0);
      s[nt] = __builtin_amdgcn_mfma_f32_16x16x32_bf16(ka[4], qb[1], s[nt], 0, 0, 0);
    }
    float lm = s[0][0];
#pragma unroll
    for (int nt = 0; nt < 8; ++nt)
#pragma unroll
      for (int r = 0; r < 4; ++r) lm = fmaxf(lm, s[nt][r]);
    float mn = fmaxf(m, lm * c2);
    float ls = 0.f;
#pragma unroll
    for (int nt = 0; nt < 8; ++nt)
#pragma unroll
      for (int r = 0; r < 4; ++r) ls += exp2f(fmaf(s[nt][r], c2, -mn));
    l = l * exp2f(m - mn) + ls;
    m = mn;
  }
  // merge the 4 quads (each covered a disjoint k-subset of the same q)
#pragma unroll
  for (int mask = 16; mask <= 32; mask <<= 1) {
    float om = __shfl_xor(m, mask, 64);
    float ol = __shfl_xor(l, mask, 64);
    float mn = fmaxf(m, om);
    l = l * exp2f(m - mn) + ol * exp2f(om - mn);
    m = mn;
  }
  const float rinv = 1.0f / l;

  // ---- sweep 2: recompute scores, write normalized P, accumulate O=P·V ----
  fx4 o[4];
#pragma unroll
  for (int d = 0; d < 4; ++d) o[d] = (fx4){0.f, 0.f, 0.f, 0.f};

  for (int t = 0; t < 16; ++t) {
    const int k0 = t * 128;
    fx4 s[8];
#pragma unroll
    for (int nt = 0; nt < 8; ++nt) s[nt] = (fx4){0.f, 0.f, 0.f, 0.f};
#pragma unroll
    for (int nt = 0; nt < 8; ++nt) {
      const s16x8* ka =
          (const s16x8*)(Kb + ((size_t)(k0 + nt * 16 + nl)) * Dd + quad * 8);
      s[nt] = __builtin_amdgcn_mfma_f32_16x16x32_bf16(ka[0], qb[0], s[nt], 0, 0, 0);
      s[nt] = __builtin_amdgcn_mfma_f32_16x16x32_bf16(ka[4], qb[1], s[nt], 0, 0, 0);
    }
#pragma unroll
    for (int nt = 0; nt < 8; ++nt) {
      fx4 p;
#pragma unroll
      for (int r = 0; r < 4; ++r)
        p[r] = exp2f(fmaf(s[nt][r], c2, -m)) * rinv;
      // attention row = q (qrow), cols k0 + nt*16 + quad*4 .. +3 (16B aligned)
      *(fx4*)(attb + (size_t)qrow * Nn + k0 + nt * 16 + quad * 4) = p;
      s16x4 pa;
      pa[0] = (short)f2bf(p[0]); pa[1] = (short)f2bf(p[1]);
      pa[2] = (short)f2bf(p[2]); pa[3] = (short)f2bf(p[3]);
#pragma unroll
      for (int ntd = 0; ntd < 4; ++ntd) {
        s16x4 vb = *(const s16x4*)(VTb + ((size_t)(ntd * 16 + nl)) * Nn + k0 +
                                   nt * 16 + quad * 4);
        o[ntd] = __builtin_amdgcn_mfma_f32_16x16x16bf16_1k(pa, vb, o[ntd], 0, 0, 0);
      }
    }
  }
  // epilogue: O C-layout -> ctx[b][q0+wave*16+quad*4+r][ntd*16+nl]
#pragma unroll
  for (int ntd = 0; ntd < 4; ++ntd)
#pragma unroll
    for (int r = 0; r < 4; ++r)
      ctx[((size_t)b * Nn + q0 + wave * 16 + quad * 4 + r) * Dd + ntd * 16 + nl] =
          o[ntd][r];
}

extern "C" void kernel_launch(void* const* d_in, const int* in_sizes, int n_in,
                              void* d_out, int out_size, void* d_ws, size_t ws_size,
                              hipStream_t stream) {
  const float* q = (const float*)d_in[0];
  const float* k = (const float*)d_in[1];
  const float* v = (const float*)d_in[2];
  const float* scale = (const float*)d_in[3];

  float* ctx = (float*)d_out;                       // [16,2048,64]
  float* att = ctx + (size_t)Bb * Nn * Dd;          // [16,2048,2048]

  // workspace: Kbf (4 MB bf16) + VTbf (4 MB bf16); rebuilt every call
  unsigned short* Kbf = (unsigned short*)d_ws;
  unsigned short* VTbf = Kbf + (size_t)Bb * Nn * Dd;

  hipLaunchKernelGGL(k_cvtK, dim3((Bb * Nn * Dd) / (256 * 4)), dim3(256), 0, stream,
                     k, Kbf);
  hipLaunchKernelGGL(k_transV, dim3(Nn / 32, Dd / 32, Bb), dim3(32, 8), 0, stream,
                     v, VTbf);
  hipLaunchKernelGGL(k_attn, dim3(Nn / 64, Bb), dim3(256), 0, stream,
                     q, Kbf, VTbf, scale, ctx, att);
}